// Round 5
// baseline (528.800 us; speedup 1.0000x reference)
//
#include <hip/hip_runtime.h>

// SASRec forward, bf16-MFMA. Round 5: T3 minimum 2-phase K-loop (2 LDS
// buffers, stage->compute->vmcnt(0)+barrier), 4 blocks/CU for TLP
// (latency-bound regime), input_seq pre-converted to bf16, bf16 residuals.
// XCD-aware bijective block swizzle (m204).
// Faithful-bug 1: attention computed for batch 0 only (attn[0] broadcast).
// Faithful-bug 2: tril-then-scale with zeros (not -inf); softmax over full row.

typedef __bf16 bf16;
typedef __bf16 bf16x8 __attribute__((ext_vector_type(8)));
typedef __bf16 bf16x4 __attribute__((ext_vector_type(4)));
typedef float  f32x4  __attribute__((ext_vector_type(4)));

#define EDIM 512
#define SEQ 512
#define NB 32
#define NH 8
#define DFFD 2048
#define NIT 2048

__device__ __forceinline__ void gl2lds16(const bf16* g, void* l) {
    __builtin_amdgcn_global_load_lds(
        (const __attribute__((address_space(1))) void*)g,
        (__attribute__((address_space(3))) void*)l, 16, 0, 0);
}

// C = act(A @ Bt^T + bias [+pos]) ; A bf16 [M][K], Bt bf16 [N][K].
// CMODE: 0 = f32 out, 1 = bf16 out, 2 = both. POS: add pos_emb[(row&511)][col].
// 2 LDS buffers, T3 minimum recipe, 1 barrier/iter, 4 blocks/CU.
template<int BM, int BN, int ACT, int CMODE, int POS, int CAUSAL>
__global__ __launch_bounds__(256, 4)
void mgemm(const bf16* __restrict__ Ab, int lda, long long sA,
           const bf16* __restrict__ Bt, int ldb, long long sB,
           const float* __restrict__ bias, const float* __restrict__ pos,
           float* __restrict__ Cf, bf16* __restrict__ Cb, int ldc, long long sC,
           int K)
{
    static_assert(BM == 128 && (BN == 128 || BN == 64), "tile");
    // ---- bijective XCD swizzle (m204) ----
    const int gx = gridDim.x, gy = gridDim.y;
    const int nwg = gx * gy;
    const int b = blockIdx.y * gx + blockIdx.x;
    const int q = nwg >> 3, r = nwg & 7;
    const int xcd = b & 7, loc = b >> 3;
    const int wg = (xcd < r ? xcd * (q + 1) : r * (q + 1) + (xcd - r) * q) + loc;
    const int bx = wg % gx, by = wg / gx;
    if (CAUSAL && bx * BN > by * BM + (BM - 1)) return;

    constexpr int TM = BM / 32, TN = BN / 32;
    constexpr int AIT = BM / 64, BIT = BN / 64;
    constexpr int ABY = BM * 64;            // bytes per A buffer (BM x 32 bf16)
    constexpr int BBY = BN * 64;
    __shared__ bf16 As[2 * BM * 32];
    __shared__ bf16 Bs[2 * BN * 32];
    char* AsB = (char*)As;
    char* BsB = (char*)Bs;
    const int tid = threadIdx.x;
    const int lane = tid & 63, wv = tid >> 6;
    const int wr = wv >> 1, wc = wv & 1;
    const int fr = lane & 15, fc = lane >> 4;
    const int row0 = by * BM, col0 = bx * BN;
    const int z = blockIdx.z;

    Ab += (long long)z * sA;
    Bt += (long long)z * sB;
    if constexpr (CMODE == 0 || CMODE == 2) Cf += (long long)z * sC;
    if constexpr (CMODE >= 1)               Cb += (long long)z * sC;

    f32x4 acc[TM][TN] = {};

    // ---- staging address precompute ----
    const bf16* aSrc[AIT];
    #pragma unroll
    for (int it = 0; it < AIT; ++it) {
        int cL = it * 256 + tid;
        int row = cL >> 2, ch = cL & 3;
        aSrc[it] = Ab + (long long)(row0 + row) * lda + ((ch ^ (row & 3)) * 8);
    }
    const bf16* bSrc[BIT];
    #pragma unroll
    for (int it = 0; it < BIT; ++it) {
        int cL = it * 256 + tid;
        int row = cL >> 2, ch = cL & 3;
        bSrc[it] = Bt + (long long)(col0 + row) * ldb + ((ch ^ (row & 3)) * 8);
    }
    // ---- fragment LDS offsets ----
    int aOff[TM], bOff[TN];
    #pragma unroll
    for (int m = 0; m < TM; ++m) {
        int row = wr * (BM / 2) + m * 16 + fr;
        aOff[m] = row * 64 + ((fc ^ (row & 3)) * 16);
    }
    #pragma unroll
    for (int n = 0; n < TN; ++n) {
        int row = wc * (BN / 2) + n * 16 + fr;
        bOff[n] = row * 64 + ((fc ^ (row & 3)) * 16);
    }

    auto stageTo = [&](int buf, int kt) {
        #pragma unroll
        for (int it = 0; it < AIT; ++it)
            gl2lds16(aSrc[it] + kt, AsB + buf * ABY + it * 4096 + wv * 1024);
        #pragma unroll
        for (int it = 0; it < BIT; ++it)
            gl2lds16(bSrc[it] + kt, BsB + buf * BBY + it * 4096 + wv * 1024);
    };

    const int nt = K >> 5;
    // ---- prologue: stage tile 0 ----
    stageTo(0, 0);
    asm volatile("s_waitcnt vmcnt(0)" ::: "memory");
    __builtin_amdgcn_s_barrier();

    int cur = 0;
    for (int t = 0; t < nt; ++t) {
        if (t + 1 < nt) stageTo(cur ^ 1, (t + 1) * 32);
        bf16x8 a[TM], b2[TN];
        #pragma unroll
        for (int m = 0; m < TM; ++m) a[m] = *(const bf16x8*)(AsB + cur * ABY + aOff[m]);
        #pragma unroll
        for (int n = 0; n < TN; ++n) b2[n] = *(const bf16x8*)(BsB + cur * BBY + bOff[n]);
        __builtin_amdgcn_s_setprio(1);
        #pragma unroll
        for (int m = 0; m < TM; ++m)
            #pragma unroll
            for (int n = 0; n < TN; ++n)
                acc[m][n] = __builtin_amdgcn_mfma_f32_16x16x32_bf16(a[m], b2[n], acc[m][n], 0, 0, 0);
        __builtin_amdgcn_s_setprio(0);
        if (t + 1 < nt) {
            asm volatile("s_waitcnt vmcnt(0)" ::: "memory");
            __builtin_amdgcn_s_barrier();
            cur ^= 1;
        }
    }

    // ---- epilogue ----
    #pragma unroll
    for (int n = 0; n < TN; ++n) {
        int col = col0 + wc * (BN / 2) + n * 16 + fr;
        float bb = bias ? bias[col] : 0.f;
        #pragma unroll
        for (int m = 0; m < TM; ++m) {
            int rbase = row0 + wr * (BM / 2) + m * 16 + fc * 4;
            #pragma unroll
            for (int rr = 0; rr < 4; ++rr) {
                float x = acc[m][n][rr] + bb;
                if constexpr (POS) x += pos[((rbase + rr) & 511) * 512 + col];
                if constexpr (ACT) x = fmaxf(x, 0.f);
                long long ci = (long long)(rbase + rr) * ldc + col;
                if constexpr (CMODE == 0 || CMODE == 2) Cf[ci] = x;
                if constexpr (CMODE >= 1)               Cb[ci] = (bf16)x;
            }
        }
    }
}

// f32 -> bf16 bulk convert (8 elems/thread/iter, grid-stride)
__global__ __launch_bounds__(256)
void cvt_k(const float* __restrict__ in, bf16* __restrict__ outb, long long n8)
{
    long long i = (long long)blockIdx.x * 256 + threadIdx.x;
    const long long stride = (long long)gridDim.x * 256;
    for (; i < n8; i += stride) {
        const float* p = in + i * 8;
        float4 u = *(const float4*)p;
        float4 v = *(const float4*)(p + 4);
        bf16x8 w8;
        w8[0] = (bf16)u.x; w8[1] = (bf16)u.y; w8[2] = (bf16)u.z; w8[3] = (bf16)u.w;
        w8[4] = (bf16)v.x; w8[5] = (bf16)v.y; w8[6] = (bf16)v.z; w8[7] = (bf16)v.w;
        *(bf16x8*)(outb + i * 8) = w8;
    }
}

// W [K][N] f32  ->  WT [N][K] bf16   (32x32 LDS tiles)
__global__ __launch_bounds__(256)
void wt_k(const float* __restrict__ W, bf16* __restrict__ WT, int K, int N)
{
    __shared__ float t[32][33];
    int n0 = blockIdx.x * 32, k0 = blockIdx.y * 32;
    int r = threadIdx.x >> 3, c4 = (threadIdx.x & 7) * 4;
    float4 v = *(const float4*)&W[(long long)(k0 + r) * N + n0 + c4];
    t[r][c4 + 0] = v.x; t[r][c4 + 1] = v.y;
    t[r][c4 + 2] = v.z; t[r][c4 + 3] = v.w;
    __syncthreads();
    int n = threadIdx.x >> 3, kk4 = (threadIdx.x & 7) * 4;
    bf16x4 o;
    o[0] = (bf16)t[kk4 + 0][n]; o[1] = (bf16)t[kk4 + 1][n];
    o[2] = (bf16)t[kk4 + 2][n]; o[3] = (bf16)t[kk4 + 3][n];
    *(bf16x4*)&WT[(long long)(n0 + n) * K + k0 + kk4] = o;
}

// pack bq|bk|bv -> qkvB[2][1536]
__global__ __launch_bounds__(512)
void packb_k(const float* __restrict__ bq, const float* __restrict__ bk,
             const float* __restrict__ bv, float* __restrict__ dst)
{
    int l = blockIdx.x, t = threadIdx.x;
    dst[l * 1536 + t]        = bq[l * 512 + t];
    dst[l * 1536 + 512 + t]  = bk[l * 512 + t];
    dst[l * 1536 + 1024 + t] = bv[l * 512 + t];
}

// VT[h][d][s] = qkv[s][1024 + h*64 + d]   (bf16 64x64 LDS transpose)
__global__ __launch_bounds__(256)
void vt_k(const bf16* __restrict__ qkv, bf16* __restrict__ VT)
{
    __shared__ bf16 t[64][80];
    int h = blockIdx.y, s0 = blockIdx.x * 64;
    int r = threadIdx.x >> 2, c16 = (threadIdx.x & 3) * 16;
    const bf16* src = qkv + (long long)(s0 + r) * 1536 + 1024 + h * 64 + c16;
    *(bf16x8*)&t[r][c16]     = *(const bf16x8*)src;
    *(bf16x8*)&t[r][c16 + 8] = *(const bf16x8*)(src + 8);
    __syncthreads();
    int d = r, seg = c16;
    bf16 tmp[16];
    #pragma unroll
    for (int j = 0; j < 16; ++j) tmp[j] = t[seg + j][d];
    bf16* dst = VT + ((long long)(h * 64 + d)) * 512 + s0 + seg;
    *(bf16x8*)dst       = *(bf16x8*)&tmp[0];
    *(bf16x8*)(dst + 8) = *(bf16x8*)&tmp[8];
}

// masked-scale softmax: f32 scores in, bf16 probs out (full row incl. masked)
__global__ __launch_bounds__(256)
void softmax_k(const float* __restrict__ sc, bf16* __restrict__ pr)
{
    int row = blockIdx.x, h = blockIdx.y;
    const float* p = sc + ((long long)(h * SEQ + row)) * SEQ;
    bf16* o = pr + ((long long)(h * SEQ + row)) * SEQ;
    int tid = threadIdx.x;
    int j1 = tid + 256;
    float v0 = 0.f, v1 = 0.f;
    if (tid <= row) v0 = p[tid] * 0.125f;
    if (j1  <= row) v1 = p[j1]  * 0.125f;
    float m = fmaxf(v0, v1);
    #pragma unroll
    for (int off = 32; off; off >>= 1) m = fmaxf(m, __shfl_xor(m, off));
    __shared__ float red[4];
    if ((tid & 63) == 0) red[tid >> 6] = m;
    __syncthreads();
    m = fmaxf(fmaxf(red[0], red[1]), fmaxf(red[2], red[3]));
    float e0 = __expf(v0 - m);
    float e1 = __expf(v1 - m);
    float s = e0 + e1;
    #pragma unroll
    for (int off = 32; off; off >>= 1) s += __shfl_xor(s, off);
    __syncthreads();
    if ((tid & 63) == 0) red[tid >> 6] = s;
    __syncthreads();
    s = red[0] + red[1] + red[2] + red[3];
    float inv = 1.f / s;
    o[tid] = (bf16)(e0 * inv);
    o[j1]  = (bf16)(e1 * inv);
}

// x[row] = LN(x[row] + res[row & mask]) ; res is bf16; writes f32 x + bf16 xb
__global__ __launch_bounds__(128)
void addln_k(float* __restrict__ x, bf16* __restrict__ xb,
             const bf16* __restrict__ res, unsigned resMask,
             const float* __restrict__ g, const float* __restrict__ bta)
{
    long long row = blockIdx.x;
    int tid = threadIdx.x;
    int c = tid * 4;
    float4 xv = *(float4*)&x[row * 512 + c];
    bf16x4 rv = *(const bf16x4*)&res[(long long)(blockIdx.x & resMask) * 512 + c];
    xv.x += (float)rv[0]; xv.y += (float)rv[1];
    xv.z += (float)rv[2]; xv.w += (float)rv[3];
    float s = xv.x + xv.y + xv.z + xv.w;
    float qq = xv.x * xv.x + xv.y * xv.y + xv.z * xv.z + xv.w * xv.w;
    #pragma unroll
    for (int off = 32; off; off >>= 1) {
        s += __shfl_xor(s, off);
        qq += __shfl_xor(qq, off);
    }
    __shared__ float rs[2], rq[2];
    if ((tid & 63) == 0) { rs[tid >> 6] = s; rq[tid >> 6] = qq; }
    __syncthreads();
    s = rs[0] + rs[1]; qq = rq[0] + rq[1];
    float mean = s * (1.0f / 512.0f);
    float var  = qq * (1.0f / 512.0f) - mean * mean;
    float rstd = rsqrtf(var + 1e-5f);
    float4 gv = *(const float4*)&g[c];
    float4 bv = *(const float4*)&bta[c];
    float4 o;
    o.x = (xv.x - mean) * rstd * gv.x + bv.x;
    o.y = (xv.y - mean) * rstd * gv.y + bv.y;
    o.z = (xv.z - mean) * rstd * gv.z + bv.z;
    o.w = (xv.w - mean) * rstd * gv.w + bv.w;
    *(float4*)&x[row * 512 + c] = o;
    bf16* xo = xb + row * 512 + c;
    xo[0] = (bf16)o.x; xo[1] = (bf16)o.y; xo[2] = (bf16)o.z; xo[3] = (bf16)o.w;
}

// out[row] = dot(x[row,:], fcW) + fcb
__global__ __launch_bounds__(256)
void fc_k(const float* __restrict__ x, const float* __restrict__ w,
          const float* __restrict__ bb, float* __restrict__ out)
{
    int row  = blockIdx.x * 4 + (threadIdx.x >> 6);
    int lane = threadIdx.x & 63;
    const float* xr = x + (long long)row * 512;
    float4 a0 = *(const float4*)&xr[lane * 8];
    float4 a1 = *(const float4*)&xr[lane * 8 + 4];
    float4 w0 = *(const float4*)&w[lane * 8];
    float4 w1 = *(const float4*)&w[lane * 8 + 4];
    float s = a0.x * w0.x + a0.y * w0.y + a0.z * w0.z + a0.w * w0.w
            + a1.x * w1.x + a1.y * w1.y + a1.z * w1.z + a1.w * w1.w;
    #pragma unroll
    for (int off = 32; off; off >>= 1) s += __shfl_xor(s, off);
    if (lane == 0) out[row] = s + bb[0];
}

extern "C" void kernel_launch(void* const* d_in, const int* in_sizes, int n_in,
                              void* d_out, int out_size, void* d_ws, size_t ws_size,
                              hipStream_t stream)
{
    const float* input_seq = (const float*)d_in[0];
    const float* emb_W  = (const float*)d_in[1];
    const float* emb_b  = (const float*)d_in[2];
    const float* pos_emb= (const float*)d_in[3];
    const float* Wq = (const float*)d_in[4];
    const float* bq = (const float*)d_in[5];
    const float* Wk = (const float*)d_in[6];
    const float* bk = (const float*)d_in[7];
    const float* Wv = (const float*)d_in[8];
    const float* bv = (const float*)d_in[9];
    const float* Wo = (const float*)d_in[10];
    const float* bo = (const float*)d_in[11];
    const float* ln1_g = (const float*)d_in[12];
    const float* ln1_b = (const float*)d_in[13];
    const float* W1 = (const float*)d_in[14];
    const float* b1 = (const float*)d_in[15];
    const float* W2 = (const float*)d_in[16];
    const float* b2 = (const float*)d_in[17];
    const float* ln2_g = (const float*)d_in[18];
    const float* ln2_b = (const float*)d_in[19];
    const float* fcW = (const float*)d_in[20];
    const float* fcb = (const float*)d_in[21];
    float* out = (float*)d_out;

    // ---- workspace layout ----
    char* w = (char*)d_ws;
    size_t off = 0;
    auto alloc = [&](size_t b) -> void* {
        off = (off + 255) & ~(size_t)255;
        void* p = w + off;
        off += b;
        return p;
    };
    float* xbuf   = (float*)alloc(16384ull * 512 * 4);   // 32 MB
    bf16*  xb     = (bf16*) alloc(16384ull * 512 * 2);   // 16 MB
    bf16*  embWT  = (bf16*) alloc(512ull * 2048 * 2);
    bf16*  qkvWT  = (bf16*) alloc(2ull * 1536 * 512 * 2);
    bf16*  WoT    = (bf16*) alloc(2ull * 512 * 512 * 2);
    bf16*  W1T    = (bf16*) alloc(2ull * 2048 * 512 * 2);
    bf16*  W2T    = (bf16*) alloc(2ull * 512 * 2048 * 2);
    float* qkvB   = (float*)alloc(2ull * 1536 * 4);
    off = (off + 255) & ~(size_t)255;
    size_t dyn0 = off;
    char* dynp = w + dyn0;
    // overlay 1 (embedding phase): input_seq as bf16, 64 MB
    bf16*  seqb     = (bf16*)dynp;                         // 16384 x 2048
    // overlay 2 (attention phase, 16.25 MB)
    bf16*  qkv      = (bf16*)dynp;                         // 512x1536
    float* scores   = (float*)(dynp + 1572864);            // 8x512x512 f32
    bf16*  probs    = (bf16*)(dynp + 1572864 + 8388608);   // 8x512x512 bf16
    bf16*  VT       = (bf16*)(dynp + 1572864 + 8388608 + 4194304);
    bf16*  attn0b   = (bf16*)(dynp + 1572864 + 8388608 + 4194304 + 524288);
    bf16*  attnout0b= (bf16*)(dynp + 1572864 + 8388608 + 4194304 + 524288 + 524288);
    // overlay 3 (FFN phase): hidden bf16 [R][2048] + ffout bf16 [R][512]
    size_t dynbytes = ws_size > dyn0 ? ws_size - dyn0 : 0;
    long long Rll = (long long)(dynbytes / 6144) & ~127ll;
    int R = (int)(Rll > 16384 ? 16384 : Rll);
    if (R < 128) R = 128;
    bf16*  hidden = (bf16*)dynp;
    bf16*  ffout  = (bf16*)(dynp + (size_t)R * 4096);

    dim3 blk(256);

    // ---- weight conversion (transposed bf16) + input conversion ----
    wt_k<<<dim3(16, 64), blk, 0, stream>>>(emb_W, embWT, 2048, 512);
    for (int l = 0; l < 2; ++l) {
        wt_k<<<dim3(16, 16), blk, 0, stream>>>(Wq + l * 262144, qkvWT + l * 786432,          512, 512);
        wt_k<<<dim3(16, 16), blk, 0, stream>>>(Wk + l * 262144, qkvWT + l * 786432 + 262144, 512, 512);
        wt_k<<<dim3(16, 16), blk, 0, stream>>>(Wv + l * 262144, qkvWT + l * 786432 + 524288, 512, 512);
        wt_k<<<dim3(16, 16), blk, 0, stream>>>(Wo + l * 262144, WoT + l * 262144, 512, 512);
        wt_k<<<dim3(64, 16), blk, 0, stream>>>(W1 + l * 1048576, W1T + l * 1048576, 512, 2048);
        wt_k<<<dim3(16, 64), blk, 0, stream>>>(W2 + l * 1048576, W2T + l * 1048576, 2048, 512);
    }
    packb_k<<<dim3(2), dim3(512), 0, stream>>>(bq, bk, bv, qkvB);
    cvt_k<<<dim3(2048), blk, 0, stream>>>(input_seq, seqb, 16384ll * 2048 / 8);

    // ---- embedding: x = seqb @ emb_W + emb_b + pos_emb ; dual-write ----
    mgemm<128, 128, 0, 2, 1, 0><<<dim3(4, 128), blk, 0, stream>>>(
        seqb, 2048, 0, embWT, 2048, 0, emb_b, pos_emb,
        xbuf, xb, 512, 0, 2048);

    for (int l = 0; l < 2; ++l) {
        const bf16* qkvWT_l = qkvWT + l * 786432;
        const bf16* WoT_l   = WoT + l * 262144;
        const bf16* W1T_l   = W1T + l * 1048576;
        const bf16* W2T_l   = W2T + l * 1048576;

        // QKV projection (batch 0 rows only), packed N=1536, bf16 out
        mgemm<128, 128, 0, 1, 0, 0><<<dim3(12, 4), blk, 0, stream>>>(
            xb, 512, 0, qkvWT_l, 512, 0, qkvB + l * 1536, nullptr,
            nullptr, qkv, 1536, 0, 512);
        // scores[h] = Qh @ Kh^T (causal tile skip), f32 out
        mgemm<128, 128, 0, 0, 0, 1><<<dim3(4, 4, 8), blk, 0, stream>>>(
            qkv, 1536, 64, qkv + 512, 1536, 64, nullptr, nullptr,
            scores, nullptr, 512, 262144, 64);
        softmax_k<<<dim3(512, 8), blk, 0, stream>>>(scores, probs);
        vt_k<<<dim3(8, 8), blk, 0, stream>>>(qkv, VT);
        // attn0 = probs @ V (per head, N=64), bf16 out
        mgemm<128, 64, 0, 1, 0, 0><<<dim3(1, 4, 8), blk, 0, stream>>>(
            probs, 512, 262144, VT, 512, 32768, nullptr, nullptr,
            nullptr, attn0b, 512, 64, 512);
        // attnout0 = attn0 @ Wo + bo, bf16 out
        mgemm<128, 128, 0, 1, 0, 0><<<dim3(4, 4), blk, 0, stream>>>(
            attn0b, 512, 0, WoT_l, 512, 0, bo + l * 512, nullptr,
            nullptr, attnout0b, 512, 0, 512);
        // x = LN1(x + attnout0[s]) broadcast
        addln_k<<<dim3(16384), dim3(128), 0, stream>>>(
            xbuf, xb, attnout0b, 511u, ln1_g + l * 512, ln1_b + l * 512);

        // ---- FFN, chunked by R rows ----
        for (int r0 = 0; r0 < 16384; r0 += R) {
            int Mc = 16384 - r0 < R ? 16384 - r0 : R;
            mgemm<128, 128, 1, 1, 0, 0><<<dim3(16, Mc / 128), blk, 0, stream>>>(
                xb + (long long)r0 * 512, 512, 0, W1T_l, 512, 0, b1 + l * 2048,
                nullptr, nullptr, hidden, 2048, 0, 512);
            if ((Mc / 128) * 4 >= 224) {
                mgemm<128, 128, 0, 1, 0, 0><<<dim3(4, Mc / 128), blk, 0, stream>>>(
                    hidden, 2048, 0, W2T_l, 2048, 0, b2 + l * 512, nullptr,
                    nullptr, ffout, 512, 0, 2048);
            } else {
                mgemm<128, 64, 0, 1, 0, 0><<<dim3(8, Mc / 128), blk, 0, stream>>>(
                    hidden, 2048, 0, W2T_l, 2048, 0, b2 + l * 512, nullptr,
                    nullptr, ffout, 512, 0, 2048);
            }
            addln_k<<<dim3(Mc), dim3(128), 0, stream>>>(
                xbuf + (long long)r0 * 512, xb + (long long)r0 * 512, ffout,
                0xffffffffu, ln2_g + l * 512, ln2_b + l * 512);
        }
    }

    // ---- out = x @ fc_W + fc_b ----
    fc_k<<<dim3(4096), blk, 0, stream>>>(xbuf, fcW, fcb, out);
}

// Round 6
// 475.127 us; speedup vs baseline: 1.1130x; 1.1130x over previous
//
#include <hip/hip_runtime.h>

// SASRec forward, bf16-MFMA. Round 6: 256-wide-tile BK=64 8-wave GEMM
// (mgemm2, m201-geometry, double-buffered, full-tile-cover prefetch,
// quadrant sub-phases) for embedding/W1/W2; 128x128 2-phase template for
// the small attention GEMMs. XCD-aware bijective block swizzle (m204).
// Faithful-bug 1: attention computed for batch 0 only (attn[0] broadcast).
// Faithful-bug 2: tril-then-scale with zeros (not -inf); softmax over full row.

typedef __bf16 bf16;
typedef __bf16 bf16x8 __attribute__((ext_vector_type(8)));
typedef __bf16 bf16x4 __attribute__((ext_vector_type(4)));
typedef float  f32x4  __attribute__((ext_vector_type(4)));

#define EDIM 512
#define SEQ 512
#define NB 32
#define NH 8
#define DFFD 2048
#define NIT 2048

__device__ __forceinline__ void gl2lds16(const bf16* g, void* l) {
    __builtin_amdgcn_global_load_lds(
        (const __attribute__((address_space(1))) void*)g,
        (__attribute__((address_space(3))) void*)l, 16, 0, 0);
}

// ============================================================================
// mgemm2: C = act(A @ Bt^T + bias [+pos]); A bf16 [M][K], Bt bf16 [N][K].
// BM=256, BN in {128,256}, BK=64, 512 threads / 8 waves, double-buffered LDS,
// stage(t+1) issued right after the switch barrier (full-tile latency cover),
// one vmcnt(0)+s_barrier per K-tile, 4 quadrant sub-phases.
// CMODE: 0 = f32 out, 1 = bf16 out, 2 = both. POS: add pos[(row&511)][col].
// ============================================================================
template<int BN, int ACT, int CMODE, int POS>
__global__ __launch_bounds__(512, 2)
void mgemm2(const bf16* __restrict__ Ab, int lda,
            const bf16* __restrict__ Bt, int ldb,
            const float* __restrict__ bias, const float* __restrict__ pos,
            float* __restrict__ Cf, bf16* __restrict__ Cb, int ldc, int K)
{
    constexpr int BM = 256, BK = 64;
    constexpr int WN = (BN == 256 ? 4 : 2);     // wave grid cols
    constexpr int WM = 8 / WN;                  // wave grid rows (2 or 4)
    constexpr int MR = BM / WM / 16;            // m frags per wave (8 or 4)
    constexpr int NR = BN / WN / 16;            // n frags per wave (4)
    constexpr int ABY = BM * BK * 2;            // 32768 bytes per A buffer
    constexpr int BBY = BN * BK * 2;            // 32768 / 16384
    constexpr int APASS = ABY / 8192;           // 4 staging passes (512 thr x 16B)
    constexpr int BPASS = BBY / 8192;           // 4 or 2

    // ---- bijective XCD swizzle (m204) ----
    const int gx = gridDim.x, gy = gridDim.y;
    const int nwg = gx * gy;
    const int b = blockIdx.y * gx + blockIdx.x;
    const int q = nwg >> 3, r = nwg & 7;
    const int xcd = b & 7, loc = b >> 3;
    const int wg = (xcd < r ? xcd * (q + 1) : r * (q + 1) + (xcd - r) * q) + loc;
    const int bx = wg % gx, by = wg / gx;
    const int row0 = by * BM, col0 = bx * BN;

    __shared__ __align__(1024) char smem[2 * (ABY + BBY)];
    char* AsB = smem;                 // [2][ABY]
    char* BsB = smem + 2 * ABY;       // [2][BBY]

    const int tid = threadIdx.x;
    const int lane = tid & 63;
    const int wv = tid >> 6;
    const int wr = wv / WN, wc = wv % WN;
    const int fr = lane & 15, fc = lane >> 4;

    // ---- staging sources (pre-swizzled global, linear LDS dest) ----
    const int srow = tid >> 3;                       // 0..63
    const int swzEl = ((tid & 7) ^ (srow & 7)) * 8;  // element offset of 16B chunk
    const bf16* aS[APASS];
    #pragma unroll
    for (int p = 0; p < APASS; ++p)
        aS[p] = Ab + (long long)(row0 + p * 64 + srow) * lda + swzEl;
    const bf16* bS[BPASS];
    #pragma unroll
    for (int p = 0; p < BPASS; ++p)
        bS[p] = Bt + (long long)(col0 + p * 64 + srow) * ldb + swzEl;

    // ---- fragment LDS addressing ----
    // row = (waveRow + mi*16 + fr); byte = row*128 + ((kk*4+fc)^(fr&7))*16
    const int aBase = (wr * (BM / WM) + fr) * 128;
    const int bBase = (wc * (BN / WN) + fr) * 128;
    int cOff[2];
    cOff[0] = ((0 + fc) ^ (fr & 7)) * 16;
    cOff[1] = ((4 + fc) ^ (fr & 7)) * 16;

    auto stage = [&](int buf, int kt) {
        #pragma unroll
        for (int p = 0; p < APASS; ++p)
            gl2lds16(aS[p] + kt, AsB + buf * ABY + (p * 512 + tid) * 16);
        #pragma unroll
        for (int p = 0; p < BPASS; ++p)
            gl2lds16(bS[p] + kt, BsB + buf * BBY + (p * 512 + tid) * 16);
    };

    f32x4 acc[MR][NR] = {};
    const int nt = K >> 6;

    stage(0, 0);

    const int QMH[4] = {0, 1, 1, 0};
    const int QNH[4] = {0, 0, 1, 1};

    for (int t = 0; t < nt; ++t) {
        const int cur = t & 1;
        asm volatile("s_waitcnt vmcnt(0)" ::: "memory");
        __builtin_amdgcn_s_barrier();
        asm volatile("" ::: "memory");
        if (t + 1 < nt) stage(cur ^ 1, (t + 1) * 64);

        #pragma unroll
        for (int ph = 0; ph < 4; ++ph) {
            const int mh = QMH[ph] * (MR / 2);
            const int nh = QNH[ph] * (NR / 2);
            bf16x8 af[MR / 2][2], bfr[NR / 2][2];
            #pragma unroll
            for (int i = 0; i < MR / 2; ++i)
                #pragma unroll
                for (int kk = 0; kk < 2; ++kk)
                    af[i][kk] = *(const bf16x8*)(AsB + cur * ABY + aBase +
                                                 (mh + i) * 2048 + cOff[kk]);
            #pragma unroll
            for (int j = 0; j < NR / 2; ++j)
                #pragma unroll
                for (int kk = 0; kk < 2; ++kk)
                    bfr[j][kk] = *(const bf16x8*)(BsB + cur * BBY + bBase +
                                                  (nh + j) * 2048 + cOff[kk]);
            __builtin_amdgcn_s_setprio(1);
            #pragma unroll
            for (int i = 0; i < MR / 2; ++i)
                #pragma unroll
                for (int j = 0; j < NR / 2; ++j)
                    #pragma unroll
                    for (int kk = 0; kk < 2; ++kk)
                        acc[mh + i][nh + j] = __builtin_amdgcn_mfma_f32_16x16x32_bf16(
                            af[i][kk], bfr[j][kk], acc[mh + i][nh + j], 0, 0, 0);
            __builtin_amdgcn_s_setprio(0);
            __builtin_amdgcn_sched_barrier(0);
        }
    }

    // ---- epilogue ----
    #pragma unroll
    for (int n = 0; n < NR; ++n) {
        int col = col0 + wc * (BN / WN) + n * 16 + fr;
        float bb = bias ? bias[col] : 0.f;
        #pragma unroll
        for (int m = 0; m < MR; ++m) {
            int rbase = row0 + wr * (BM / WM) + m * 16 + fc * 4;
            #pragma unroll
            for (int rr = 0; rr < 4; ++rr) {
                float x = acc[m][n][rr] + bb;
                if constexpr (POS) x += pos[((rbase + rr) & 511) * 512 + col];
                if constexpr (ACT) x = fmaxf(x, 0.f);
                long long ci = (long long)(rbase + rr) * ldc + col;
                if constexpr (CMODE == 0 || CMODE == 2) Cf[ci] = x;
                if constexpr (CMODE >= 1)               Cb[ci] = (bf16)x;
            }
        }
    }
}

// ============================================================================
// mgemm: 128x128 (or 128x64) 2-phase template for the small attention GEMMs.
// ============================================================================
template<int BM, int BN, int ACT, int CMODE, int POS, int CAUSAL>
__global__ __launch_bounds__(256, 4)
void mgemm(const bf16* __restrict__ Ab, int lda, long long sA,
           const bf16* __restrict__ Bt, int ldb, long long sB,
           const float* __restrict__ bias, const float* __restrict__ pos,
           float* __restrict__ Cf, bf16* __restrict__ Cb, int ldc, long long sC,
           int K)
{
    static_assert(BM == 128 && (BN == 128 || BN == 64), "tile");
    const int gx = gridDim.x, gy = gridDim.y;
    const int nwg = gx * gy;
    const int b = blockIdx.y * gx + blockIdx.x;
    const int q = nwg >> 3, r = nwg & 7;
    const int xcd = b & 7, loc = b >> 3;
    const int wg = (xcd < r ? xcd * (q + 1) : r * (q + 1) + (xcd - r) * q) + loc;
    const int bx = wg % gx, by = wg / gx;
    if (CAUSAL && bx * BN > by * BM + (BM - 1)) return;

    constexpr int TM = BM / 32, TN = BN / 32;
    constexpr int AIT = BM / 64, BIT = BN / 64;
    constexpr int ABY = BM * 64;
    constexpr int BBY = BN * 64;
    __shared__ bf16 As[2 * BM * 32];
    __shared__ bf16 Bs[2 * BN * 32];
    char* AsB = (char*)As;
    char* BsB = (char*)Bs;
    const int tid = threadIdx.x;
    const int lane = tid & 63, wv = tid >> 6;
    const int wr = wv >> 1, wc = wv & 1;
    const int fr = lane & 15, fc = lane >> 4;
    const int row0 = by * BM, col0 = bx * BN;
    const int z = blockIdx.z;

    Ab += (long long)z * sA;
    Bt += (long long)z * sB;
    if constexpr (CMODE == 0 || CMODE == 2) Cf += (long long)z * sC;
    if constexpr (CMODE >= 1)               Cb += (long long)z * sC;

    f32x4 acc[TM][TN] = {};

    const bf16* aSrc[AIT];
    #pragma unroll
    for (int it = 0; it < AIT; ++it) {
        int cL = it * 256 + tid;
        int row = cL >> 2, ch = cL & 3;
        aSrc[it] = Ab + (long long)(row0 + row) * lda + ((ch ^ (row & 3)) * 8);
    }
    const bf16* bSrc[BIT];
    #pragma unroll
    for (int it = 0; it < BIT; ++it) {
        int cL = it * 256 + tid;
        int row = cL >> 2, ch = cL & 3;
        bSrc[it] = Bt + (long long)(col0 + row) * ldb + ((ch ^ (row & 3)) * 8);
    }
    int aOff[TM], bOff[TN];
    #pragma unroll
    for (int m = 0; m < TM; ++m) {
        int row = wr * (BM / 2) + m * 16 + fr;
        aOff[m] = row * 64 + ((fc ^ (row & 3)) * 16);
    }
    #pragma unroll
    for (int n = 0; n < TN; ++n) {
        int row = wc * (BN / 2) + n * 16 + fr;
        bOff[n] = row * 64 + ((fc ^ (row & 3)) * 16);
    }

    auto stageTo = [&](int buf, int kt) {
        #pragma unroll
        for (int it = 0; it < AIT; ++it)
            gl2lds16(aSrc[it] + kt, AsB + buf * ABY + it * 4096 + wv * 1024);
        #pragma unroll
        for (int it = 0; it < BIT; ++it)
            gl2lds16(bSrc[it] + kt, BsB + buf * BBY + it * 4096 + wv * 1024);
    };

    const int nt = K >> 5;
    stageTo(0, 0);
    asm volatile("s_waitcnt vmcnt(0)" ::: "memory");
    __builtin_amdgcn_s_barrier();
    asm volatile("" ::: "memory");

    int cur = 0;
    for (int t = 0; t < nt; ++t) {
        if (t + 1 < nt) stageTo(cur ^ 1, (t + 1) * 32);
        bf16x8 a[TM], b2[TN];
        #pragma unroll
        for (int m = 0; m < TM; ++m) a[m] = *(const bf16x8*)(AsB + cur * ABY + aOff[m]);
        #pragma unroll
        for (int n = 0; n < TN; ++n) b2[n] = *(const bf16x8*)(BsB + cur * BBY + bOff[n]);
        __builtin_amdgcn_s_setprio(1);
        #pragma unroll
        for (int m = 0; m < TM; ++m)
            #pragma unroll
            for (int n = 0; n < TN; ++n)
                acc[m][n] = __builtin_amdgcn_mfma_f32_16x16x32_bf16(a[m], b2[n], acc[m][n], 0, 0, 0);
        __builtin_amdgcn_s_setprio(0);
        if (t + 1 < nt) {
            asm volatile("s_waitcnt vmcnt(0)" ::: "memory");
            __builtin_amdgcn_s_barrier();
            asm volatile("" ::: "memory");
            cur ^= 1;
        }
    }

    #pragma unroll
    for (int n = 0; n < TN; ++n) {
        int col = col0 + wc * (BN / 2) + n * 16 + fr;
        float bb = bias ? bias[col] : 0.f;
        #pragma unroll
        for (int m = 0; m < TM; ++m) {
            int rbase = row0 + wr * (BM / 2) + m * 16 + fc * 4;
            #pragma unroll
            for (int rr = 0; rr < 4; ++rr) {
                float x = acc[m][n][rr] + bb;
                if constexpr (POS) x += pos[((rbase + rr) & 511) * 512 + col];
                if constexpr (ACT) x = fmaxf(x, 0.f);
                long long ci = (long long)(rbase + rr) * ldc + col;
                if constexpr (CMODE == 0 || CMODE == 2) Cf[ci] = x;
                if constexpr (CMODE >= 1)               Cb[ci] = (bf16)x;
            }
        }
    }
}

// f32 -> bf16 bulk convert (8 elems/thread/iter, grid-stride)
__global__ __launch_bounds__(256)
void cvt_k(const float* __restrict__ in, bf16* __restrict__ outb, long long n8)
{
    long long i = (long long)blockIdx.x * 256 + threadIdx.x;
    const long long stride = (long long)gridDim.x * 256;
    for (; i < n8; i += stride) {
        const float* p = in + i * 8;
        float4 u = *(const float4*)p;
        float4 v = *(const float4*)(p + 4);
        bf16x8 w8;
        w8[0] = (bf16)u.x; w8[1] = (bf16)u.y; w8[2] = (bf16)u.z; w8[3] = (bf16)u.w;
        w8[4] = (bf16)v.x; w8[5] = (bf16)v.y; w8[6] = (bf16)v.z; w8[7] = (bf16)v.w;
        *(bf16x8*)(outb + i * 8) = w8;
    }
}

// W [K][N] f32  ->  WT [N][K] bf16   (32x32 LDS tiles)
__global__ __launch_bounds__(256)
void wt_k(const float* __restrict__ W, bf16* __restrict__ WT, int K, int N)
{
    __shared__ float t[32][33];
    int n0 = blockIdx.x * 32, k0 = blockIdx.y * 32;
    int r = threadIdx.x >> 3, c4 = (threadIdx.x & 7) * 4;
    float4 v = *(const float4*)&W[(long long)(k0 + r) * N + n0 + c4];
    t[r][c4 + 0] = v.x; t[r][c4 + 1] = v.y;
    t[r][c4 + 2] = v.z; t[r][c4 + 3] = v.w;
    __syncthreads();
    int n = threadIdx.x >> 3, kk4 = (threadIdx.x & 7) * 4;
    bf16x4 o;
    o[0] = (bf16)t[kk4 + 0][n]; o[1] = (bf16)t[kk4 + 1][n];
    o[2] = (bf16)t[kk4 + 2][n]; o[3] = (bf16)t[kk4 + 3][n];
    *(bf16x4*)&WT[(long long)(n0 + n) * K + k0 + kk4] = o;
}

// pack bq|bk|bv -> qkvB[2][1536]
__global__ __launch_bounds__(512)
void packb_k(const float* __restrict__ bq, const float* __restrict__ bk,
             const float* __restrict__ bv, float* __restrict__ dst)
{
    int l = blockIdx.x, t = threadIdx.x;
    dst[l * 1536 + t]        = bq[l * 512 + t];
    dst[l * 1536 + 512 + t]  = bk[l * 512 + t];
    dst[l * 1536 + 1024 + t] = bv[l * 512 + t];
}

// VT[h][d][s] = qkv[s][1024 + h*64 + d]   (bf16 64x64 LDS transpose)
__global__ __launch_bounds__(256)
void vt_k(const bf16* __restrict__ qkv, bf16* __restrict__ VT)
{
    __shared__ bf16 t[64][80];
    int h = blockIdx.y, s0 = blockIdx.x * 64;
    int r = threadIdx.x >> 2, c16 = (threadIdx.x & 3) * 16;
    const bf16* src = qkv + (long long)(s0 + r) * 1536 + 1024 + h * 64 + c16;
    *(bf16x8*)&t[r][c16]     = *(const bf16x8*)src;
    *(bf16x8*)&t[r][c16 + 8] = *(const bf16x8*)(src + 8);
    __syncthreads();
    int d = r, seg = c16;
    bf16 tmp[16];
    #pragma unroll
    for (int j = 0; j < 16; ++j) tmp[j] = t[seg + j][d];
    bf16* dst = VT + ((long long)(h * 64 + d)) * 512 + s0 + seg;
    *(bf16x8*)dst       = *(bf16x8*)&tmp[0];
    *(bf16x8*)(dst + 8) = *(bf16x8*)&tmp[8];
}

// masked-scale softmax: f32 scores in, bf16 probs out (full row incl. masked)
__global__ __launch_bounds__(256)
void softmax_k(const float* __restrict__ sc, bf16* __restrict__ pr)
{
    int row = blockIdx.x, h = blockIdx.y;
    const float* p = sc + ((long long)(h * SEQ + row)) * SEQ;
    bf16* o = pr + ((long long)(h * SEQ + row)) * SEQ;
    int tid = threadIdx.x;
    int j1 = tid + 256;
    float v0 = 0.f, v1 = 0.f;
    if (tid <= row) v0 = p[tid] * 0.125f;
    if (j1  <= row) v1 = p[j1]  * 0.125f;
    float m = fmaxf(v0, v1);
    #pragma unroll
    for (int off = 32; off; off >>= 1) m = fmaxf(m, __shfl_xor(m, off));
    __shared__ float red[4];
    if ((tid & 63) == 0) red[tid >> 6] = m;
    __syncthreads();
    m = fmaxf(fmaxf(red[0], red[1]), fmaxf(red[2], red[3]));
    float e0 = __expf(v0 - m);
    float e1 = __expf(v1 - m);
    float s = e0 + e1;
    #pragma unroll
    for (int off = 32; off; off >>= 1) s += __shfl_xor(s, off);
    __syncthreads();
    if ((tid & 63) == 0) red[tid >> 6] = s;
    __syncthreads();
    s = red[0] + red[1] + red[2] + red[3];
    float inv = 1.f / s;
    o[tid] = (bf16)(e0 * inv);
    o[j1]  = (bf16)(e1 * inv);
}

// x[row] = LN(x[row] + res[row & mask]) ; res is bf16; writes f32 x + bf16 xb
__global__ __launch_bounds__(128)
void addln_k(float* __restrict__ x, bf16* __restrict__ xb,
             const bf16* __restrict__ res, unsigned resMask,
             const float* __restrict__ g, const float* __restrict__ bta)
{
    long long row = blockIdx.x;
    int tid = threadIdx.x;
    int c = tid * 4;
    float4 xv = *(float4*)&x[row * 512 + c];
    bf16x4 rv = *(const bf16x4*)&res[(long long)(blockIdx.x & resMask) * 512 + c];
    xv.x += (float)rv[0]; xv.y += (float)rv[1];
    xv.z += (float)rv[2]; xv.w += (float)rv[3];
    float s = xv.x + xv.y + xv.z + xv.w;
    float qq = xv.x * xv.x + xv.y * xv.y + xv.z * xv.z + xv.w * xv.w;
    #pragma unroll
    for (int off = 32; off; off >>= 1) {
        s += __shfl_xor(s, off);
        qq += __shfl_xor(qq, off);
    }
    __shared__ float rs[2], rq[2];
    if ((tid & 63) == 0) { rs[tid >> 6] = s; rq[tid >> 6] = qq; }
    __syncthreads();
    s = rs[0] + rs[1]; qq = rq[0] + rq[1];
    float mean = s * (1.0f / 512.0f);
    float var  = qq * (1.0f / 512.0f) - mean * mean;
    float rstd = rsqrtf(var + 1e-5f);
    float4 gv = *(const float4*)&g[c];
    float4 bv = *(const float4*)&bta[c];
    float4 o;
    o.x = (xv.x - mean) * rstd * gv.x + bv.x;
    o.y = (xv.y - mean) * rstd * gv.y + bv.y;
    o.z = (xv.z - mean) * rstd * gv.z + bv.z;
    o.w = (xv.w - mean) * rstd * gv.w + bv.w;
    *(float4*)&x[row * 512 + c] = o;
    bf16* xo = xb + row * 512 + c;
    xo[0] = (bf16)o.x; xo[1] = (bf16)o.y; xo[2] = (bf16)o.z; xo[3] = (bf16)o.w;
}

// out[row] = dot(x[row,:], fcW) + fcb
__global__ __launch_bounds__(256)
void fc_k(const float* __restrict__ x, const float* __restrict__ w,
          const float* __restrict__ bb, float* __restrict__ out)
{
    int row  = blockIdx.x * 4 + (threadIdx.x >> 6);
    int lane = threadIdx.x & 63;
    const float* xr = x + (long long)row * 512;
    float4 a0 = *(const float4*)&xr[lane * 8];
    float4 a1 = *(const float4*)&xr[lane * 8 + 4];
    float4 w0 = *(const float4*)&w[lane * 8];
    float4 w1 = *(const float4*)&w[lane * 8 + 4];
    float s = a0.x * w0.x + a0.y * w0.y + a0.z * w0.z + a0.w * w0.w
            + a1.x * w1.x + a1.y * w1.y + a1.z * w1.z + a1.w * w1.w;
    #pragma unroll
    for (int off = 32; off; off >>= 1) s += __shfl_xor(s, off);
    if (lane == 0) out[row] = s + bb[0];
}

extern "C" void kernel_launch(void* const* d_in, const int* in_sizes, int n_in,
                              void* d_out, int out_size, void* d_ws, size_t ws_size,
                              hipStream_t stream)
{
    const float* input_seq = (const float*)d_in[0];
    const float* emb_W  = (const float*)d_in[1];
    const float* emb_b  = (const float*)d_in[2];
    const float* pos_emb= (const float*)d_in[3];
    const float* Wq = (const float*)d_in[4];
    const float* bq = (const float*)d_in[5];
    const float* Wk = (const float*)d_in[6];
    const float* bk = (const float*)d_in[7];
    const float* Wv = (const float*)d_in[8];
    const float* bv = (const float*)d_in[9];
    const float* Wo = (const float*)d_in[10];
    const float* bo = (const float*)d_in[11];
    const float* ln1_g = (const float*)d_in[12];
    const float* ln1_b = (const float*)d_in[13];
    const float* W1 = (const float*)d_in[14];
    const float* b1 = (const float*)d_in[15];
    const float* W2 = (const float*)d_in[16];
    const float* b2 = (const float*)d_in[17];
    const float* ln2_g = (const float*)d_in[18];
    const float* ln2_b = (const float*)d_in[19];
    const float* fcW = (const float*)d_in[20];
    const float* fcb = (const float*)d_in[21];
    float* out = (float*)d_out;

    // ---- workspace layout ----
    char* w = (char*)d_ws;
    size_t off = 0;
    auto alloc = [&](size_t b) -> void* {
        off = (off + 255) & ~(size_t)255;
        void* p = w + off;
        off += b;
        return p;
    };
    float* xbuf   = (float*)alloc(16384ull * 512 * 4);   // 32 MB
    bf16*  xb     = (bf16*) alloc(16384ull * 512 * 2);   // 16 MB
    bf16*  embWT  = (bf16*) alloc(512ull * 2048 * 2);
    bf16*  qkvWT  = (bf16*) alloc(2ull * 1536 * 512 * 2);
    bf16*  WoT    = (bf16*) alloc(2ull * 512 * 512 * 2);
    bf16*  W1T    = (bf16*) alloc(2ull * 2048 * 512 * 2);
    bf16*  W2T    = (bf16*) alloc(2ull * 512 * 2048 * 2);
    float* qkvB   = (float*)alloc(2ull * 1536 * 4);
    off = (off + 255) & ~(size_t)255;
    size_t dyn0 = off;
    char* dynp = w + dyn0;
    // overlay 1 (embedding phase): input_seq as bf16, 64 MB
    bf16*  seqb     = (bf16*)dynp;                         // 16384 x 2048
    // overlay 2 (attention phase, 16.25 MB)
    bf16*  qkv      = (bf16*)dynp;                         // 512x1536
    float* scores   = (float*)(dynp + 1572864);            // 8x512x512 f32
    bf16*  probs    = (bf16*)(dynp + 1572864 + 8388608);   // 8x512x512 bf16
    bf16*  VT       = (bf16*)(dynp + 1572864 + 8388608 + 4194304);
    bf16*  attn0b   = (bf16*)(dynp + 1572864 + 8388608 + 4194304 + 524288);
    bf16*  attnout0b= (bf16*)(dynp + 1572864 + 8388608 + 4194304 + 524288 + 524288);
    // overlay 3 (FFN phase): hidden bf16 [R][2048] + ffout bf16 [R][512]
    size_t dynbytes = ws_size > dyn0 ? ws_size - dyn0 : 0;
    long long Rll = (long long)(dynbytes / 6144) & ~255ll;
    int R = (int)(Rll > 16384 ? 16384 : Rll);
    if (R < 256) R = 256;
    bf16*  hidden = (bf16*)dynp;
    bf16*  ffout  = (bf16*)(dynp + (size_t)R * 4096);

    dim3 blk(256);
    dim3 blk512(512);

    // ---- weight conversion (transposed bf16) + input conversion ----
    wt_k<<<dim3(16, 64), blk, 0, stream>>>(emb_W, embWT, 2048, 512);
    for (int l = 0; l < 2; ++l) {
        wt_k<<<dim3(16, 16), blk, 0, stream>>>(Wq + l * 262144, qkvWT + l * 786432,          512, 512);
        wt_k<<<dim3(16, 16), blk, 0, stream>>>(Wk + l * 262144, qkvWT + l * 786432 + 262144, 512, 512);
        wt_k<<<dim3(16, 16), blk, 0, stream>>>(Wv + l * 262144, qkvWT + l * 786432 + 524288, 512, 512);
        wt_k<<<dim3(16, 16), blk, 0, stream>>>(Wo + l * 262144, WoT + l * 262144, 512, 512);
        wt_k<<<dim3(64, 16), blk, 0, stream>>>(W1 + l * 1048576, W1T + l * 1048576, 512, 2048);
        wt_k<<<dim3(16, 64), blk, 0, stream>>>(W2 + l * 1048576, W2T + l * 1048576, 2048, 512);
    }
    packb_k<<<dim3(2), dim3(512), 0, stream>>>(bq, bk, bv, qkvB);
    cvt_k<<<dim3(2048), blk, 0, stream>>>(input_seq, seqb, 16384ll * 2048 / 8);

    // ---- embedding: x = seqb @ emb_W + emb_b + pos_emb ; dual-write ----
    mgemm2<128, 0, 2, 1><<<dim3(4, 64), blk512, 0, stream>>>(
        seqb, 2048, embWT, 2048, emb_b, pos_emb, xbuf, xb, 512, 2048);

    for (int l = 0; l < 2; ++l) {
        const bf16* qkvWT_l = qkvWT + l * 786432;
        const bf16* WoT_l   = WoT + l * 262144;
        const bf16* W1T_l   = W1T + l * 1048576;
        const bf16* W2T_l   = W2T + l * 1048576;

        // QKV projection (batch 0 rows only), packed N=1536, bf16 out
        mgemm<128, 128, 0, 1, 0, 0><<<dim3(12, 4), blk, 0, stream>>>(
            xb, 512, 0, qkvWT_l, 512, 0, qkvB + l * 1536, nullptr,
            nullptr, qkv, 1536, 0, 512);
        // scores[h] = Qh @ Kh^T (causal tile skip), f32 out
        mgemm<128, 128, 0, 0, 0, 1><<<dim3(4, 4, 8), blk, 0, stream>>>(
            qkv, 1536, 64, qkv + 512, 1536, 64, nullptr, nullptr,
            scores, nullptr, 512, 262144, 64);
        softmax_k<<<dim3(512, 8), blk, 0, stream>>>(scores, probs);
        vt_k<<<dim3(8, 8), blk, 0, stream>>>(qkv, VT);
        // attn0 = probs @ V (per head, N=64), bf16 out
        mgemm<128, 64, 0, 1, 0, 0><<<dim3(1, 4, 8), blk, 0, stream>>>(
            probs, 512, 262144, VT, 512, 32768, nullptr, nullptr,
            nullptr, attn0b, 512, 64, 512);
        // attnout0 = attn0 @ Wo + bo, bf16 out
        mgemm<128, 128, 0, 1, 0, 0><<<dim3(4, 4), blk, 0, stream>>>(
            attn0b, 512, 0, WoT_l, 512, 0, bo + l * 512, nullptr,
            nullptr, attnout0b, 512, 0, 512);
        // x = LN1(x + attnout0[s]) broadcast
        addln_k<<<dim3(16384), dim3(128), 0, stream>>>(
            xbuf, xb, attnout0b, 511u, ln1_g + l * 512, ln1_b + l * 512);

        // ---- FFN, chunked by R rows ----
        for (int r0 = 0; r0 < 16384; r0 += R) {
            int Mc = 16384 - r0 < R ? 16384 - r0 : R;
            mgemm2<256, 1, 1, 0><<<dim3(8, Mc / 256), blk512, 0, stream>>>(
                xb + (long long)r0 * 512, 512, W1T_l, 512, b1 + l * 2048,
                nullptr, nullptr, hidden, 2048, 512);
            mgemm2<128, 0, 1, 0><<<dim3(4, Mc / 256), blk512, 0, stream>>>(
                hidden, 2048, W2T_l, 2048, b2 + l * 512,
                nullptr, nullptr, ffout, 512, 2048);
            addln_k<<<dim3(Mc), dim3(128), 0, stream>>>(
                xbuf + (long long)r0 * 512, xb + (long long)r0 * 512, ffout,
                0xffffffffu, ln2_g + l * 512, ln2_b + l * 512);
        }
    }

    // ---- out = x @ fc_W + fc_b ----
    fc_k<<<dim3(4096), blk, 0, stream>>>(xbuf, fcW, fcb, out);
}

// Round 7
// 433.899 us; speedup vs baseline: 1.2187x; 1.0950x over previous
//
#include <hip/hip_runtime.h>

// SASRec forward, bf16-MFMA. Round 7:
//  - mgemm2: BK=32, NBUF=4 counted-vmcnt pipeline (steady vmcnt(2*OPT), never
//    drained mid-loop), LDS-staged coalesced bf16 epilogue (16B/lane stores).
//  - x stored bf16 only (no f32 xbuf); addln/fc read bf16.
//  - W1: 256x256 (1 blk/CU, deep pipeline). W2/emb: 128x128, VGPR<=128 -> 2 blk/CU.
//  - attention path unchanged (128x128 2-phase template).
// Faithful-bug 1: attention computed for batch 0 only (attn[0] broadcast).
// Faithful-bug 2: tril-then-scale with zeros (not -inf); softmax over full row.

typedef __bf16 bf16;
typedef __bf16 bf16x8 __attribute__((ext_vector_type(8)));
typedef __bf16 bf16x4 __attribute__((ext_vector_type(4)));
typedef float  f32x4  __attribute__((ext_vector_type(4)));

#define SEQ 512

__device__ __forceinline__ void gl2lds16(const bf16* g, void* l) {
    __builtin_amdgcn_global_load_lds(
        (const __attribute__((address_space(1))) void*)g,
        (__attribute__((address_space(3))) void*)l, 16, 0, 0);
}

template<int N> __device__ __forceinline__ void waitvm() {
    if constexpr (N == 0) asm volatile("s_waitcnt vmcnt(0)" ::: "memory");
    else if constexpr (N == 2) asm volatile("s_waitcnt vmcnt(2)" ::: "memory");
    else if constexpr (N == 4) asm volatile("s_waitcnt vmcnt(4)" ::: "memory");
    else if constexpr (N == 8) asm volatile("s_waitcnt vmcnt(8)" ::: "memory");
    else static_assert(N == 0, "unsupported waitvm");
}

// ============================================================================
// mgemm2: Cb = act(A @ Bt^T + bias [+pos]); A bf16 [M][K], Bt bf16 [N][K].
// 512 threads / 8 waves. BK=32. NBUF=4 counted-vmcnt pipeline.
// Coalesced epilogue via per-wave LDS staging. bf16 output only.
// ============================================================================
template<int BM, int BN, int ACT, int POS, int WPE>
__global__ __launch_bounds__(512, WPE)
void mgemm2(const bf16* __restrict__ Ab, int lda,
            const bf16* __restrict__ Bt, int ldb,
            const float* __restrict__ bias, const float* __restrict__ pos,
            bf16* __restrict__ Cb, int ldc, int K)
{
    constexpr int WN = (BN >= 256 ? 4 : 2);
    constexpr int WM = 8 / WN;
    constexpr int RPW = BM / WM;          // rows per wave
    constexpr int MR = RPW / 16;
    constexpr int NR = 4;                 // CPW = 64 always
    constexpr int ABY = BM * 64;          // bytes per A buffer (BM x 32 bf16)
    constexpr int BBY = BN * 64;
    constexpr int APASS = BM / 128;
    constexpr int BPASS = BN / 128;
    constexpr int OPT = APASS + BPASS;
    constexpr int NBUF = 4;
    __shared__ __align__(1024) char smem[NBUF * (ABY + BBY)];
    char* AsB = smem;
    char* BsB = smem + NBUF * ABY;

    // ---- bijective XCD swizzle (m204) ----
    const int gx = gridDim.x, gy = gridDim.y;
    const int nwg = gx * gy;
    const int b = blockIdx.y * gx + blockIdx.x;
    const int q = nwg >> 3, r = nwg & 7;
    const int xcd = b & 7, loc = b >> 3;
    const int wg = (xcd < r ? xcd * (q + 1) : r * (q + 1) + (xcd - r) * q) + loc;
    const int bx = wg % gx, by = wg / gx;
    const int row0 = by * BM, col0 = bx * BN;

    const int tid = threadIdx.x;
    const int lane = tid & 63;
    const int wv = tid >> 6;
    const int wr = wv / WN, wc = wv % WN;
    const int fr = lane & 15, fc = lane >> 4;

    // ---- staging sources (pre-swizzled global, linear LDS dest) ----
    const bf16* aS[APASS];
    #pragma unroll
    for (int p = 0; p < APASS; ++p) {
        int cL = p * 512 + tid;
        int row = cL >> 2, ch = cL & 3;
        aS[p] = Ab + (long long)(row0 + row) * lda + ((ch ^ (row & 3)) * 8);
    }
    const bf16* bS[BPASS];
    #pragma unroll
    for (int p = 0; p < BPASS; ++p) {
        int cL = p * 512 + tid;
        int row = cL >> 2, ch = cL & 3;
        bS[p] = Bt + (long long)(col0 + row) * ldb + ((ch ^ (row & 3)) * 8);
    }
    // ---- fragment LDS offsets ----
    int aOff[MR], bOff[NR];
    #pragma unroll
    for (int m = 0; m < MR; ++m) {
        int row = wr * RPW + m * 16 + fr;
        aOff[m] = row * 64 + ((fc ^ (row & 3)) * 16);
    }
    #pragma unroll
    for (int n = 0; n < NR; ++n) {
        int row = wc * 64 + n * 16 + fr;
        bOff[n] = row * 64 + ((fc ^ (row & 3)) * 16);
    }

    auto stage = [&](int buf, int kt) {
        #pragma unroll
        for (int p = 0; p < APASS; ++p)
            gl2lds16(aS[p] + kt, AsB + buf * ABY + (p * 512 + tid) * 16);
        #pragma unroll
        for (int p = 0; p < BPASS; ++p)
            gl2lds16(bS[p] + kt, BsB + buf * BBY + (p * 512 + tid) * 16);
    };

    f32x4 acc[MR][NR] = {};
    const int nt = K >> 5;

    stage(0, 0);
    if (nt > 1) stage(1, 32);
    if (nt > 2) stage(2, 64);

    for (int t = 0; t < nt; ++t) {
        const int staged = (t + 3 < nt ? t + 3 : nt);
        const int allow = (staged - t - 1) * OPT;
        if (allow >= 2 * OPT)      waitvm<2 * OPT>();
        else if (allow >= OPT)     waitvm<OPT>();
        else                       waitvm<0>();
        __builtin_amdgcn_s_barrier();
        if (t + 3 < nt) stage((t + 3) & 3, (t + 3) * 32);

        const int cur = t & 3;
        bf16x8 a[MR], b2[NR];
        #pragma unroll
        for (int m = 0; m < MR; ++m)
            a[m] = *(const bf16x8*)(AsB + cur * ABY + aOff[m]);
        #pragma unroll
        for (int n = 0; n < NR; ++n)
            b2[n] = *(const bf16x8*)(BsB + cur * BBY + bOff[n]);
        __builtin_amdgcn_s_setprio(1);
        #pragma unroll
        for (int m = 0; m < MR; ++m)
            #pragma unroll
            for (int n = 0; n < NR; ++n)
                acc[m][n] = __builtin_amdgcn_mfma_f32_16x16x32_bf16(
                    a[m], b2[n], acc[m][n], 0, 0, 0);
        __builtin_amdgcn_s_setprio(0);
    }

    // ---- coalesced epilogue: acc -> per-wave LDS slice -> 16B stores ----
    __builtin_amdgcn_s_barrier();     // all waves done reading K-loop LDS
    float* st = (float*)(smem + wv * 4096);   // f32[16][64] per wave
    const int rowb = row0 + wr * RPW;
    const int colb = col0 + wc * 64;
    #pragma unroll
    for (int m = 0; m < MR; ++m) {
        #pragma unroll
        for (int n = 0; n < NR; ++n) {
            int col = colb + n * 16 + fr;
            float bb = bias ? bias[col] : 0.f;
            #pragma unroll
            for (int rr = 0; rr < 4; ++rr) {
                float x = acc[m][n][rr] + bb;
                if constexpr (POS) {
                    int rowg = rowb + m * 16 + fc * 4 + rr;
                    x += pos[(rowg & 511) * 512 + col];
                }
                if constexpr (ACT) x = fmaxf(x, 0.f);
                st[(fc * 4 + rr) * 64 + n * 16 + fr] = x;
            }
        }
        #pragma unroll
        for (int s = 0; s < 2; ++s) {
            int row = s * 8 + (lane >> 3);
            int c8 = (lane & 7) * 8;
            f32x4 u = *(const f32x4*)&st[row * 64 + c8];
            f32x4 v = *(const f32x4*)&st[row * 64 + c8 + 4];
            bf16x8 w8;
            w8[0] = (bf16)u[0]; w8[1] = (bf16)u[1];
            w8[2] = (bf16)u[2]; w8[3] = (bf16)u[3];
            w8[4] = (bf16)v[0]; w8[5] = (bf16)v[1];
            w8[6] = (bf16)v[2]; w8[7] = (bf16)v[3];
            *(bf16x8*)&Cb[(long long)(rowb + m * 16 + row) * ldc + colb + c8] = w8;
        }
    }
}

// ============================================================================
// mgemm: 128x128 / 128x64 2-phase template for the small attention GEMMs.
// ============================================================================
template<int BM, int BN, int ACT, int CMODE, int CAUSAL>
__global__ __launch_bounds__(256, 4)
void mgemm(const bf16* __restrict__ Ab, int lda, long long sA,
           const bf16* __restrict__ Bt, int ldb, long long sB,
           const float* __restrict__ bias,
           float* __restrict__ Cf, bf16* __restrict__ Cb, int ldc, long long sC,
           int K)
{
    static_assert(BM == 128 && (BN == 128 || BN == 64), "tile");
    const int gx = gridDim.x, gy = gridDim.y;
    const int nwg = gx * gy;
    const int b = blockIdx.y * gx + blockIdx.x;
    const int q = nwg >> 3, r = nwg & 7;
    const int xcd = b & 7, loc = b >> 3;
    const int wg = (xcd < r ? xcd * (q + 1) : r * (q + 1) + (xcd - r) * q) + loc;
    const int bx = wg % gx, by = wg / gx;
    if (CAUSAL && bx * BN > by * BM + (BM - 1)) return;

    constexpr int TM = BM / 32, TN = BN / 32;
    constexpr int AIT = BM / 64, BIT = BN / 64;
    constexpr int ABY = BM * 64;
    constexpr int BBY = BN * 64;
    __shared__ bf16 As[2 * BM * 32];
    __shared__ bf16 Bs[2 * BN * 32];
    char* AsB = (char*)As;
    char* BsB = (char*)Bs;
    const int tid = threadIdx.x;
    const int lane = tid & 63, wv = tid >> 6;
    const int wr = wv >> 1, wc = wv & 1;
    const int fr = lane & 15, fc = lane >> 4;
    const int row0 = by * BM, col0 = bx * BN;
    const int z = blockIdx.z;

    Ab += (long long)z * sA;
    Bt += (long long)z * sB;
    if constexpr (CMODE == 0) Cf += (long long)z * sC;
    else                      Cb += (long long)z * sC;

    f32x4 acc[TM][TN] = {};

    const bf16* aSrc[AIT];
    #pragma unroll
    for (int it = 0; it < AIT; ++it) {
        int cL = it * 256 + tid;
        int row = cL >> 2, ch = cL & 3;
        aSrc[it] = Ab + (long long)(row0 + row) * lda + ((ch ^ (row & 3)) * 8);
    }
    const bf16* bSrc[BIT];
    #pragma unroll
    for (int it = 0; it < BIT; ++it) {
        int cL = it * 256 + tid;
        int row = cL >> 2, ch = cL & 3;
        bSrc[it] = Bt + (long long)(col0 + row) * ldb + ((ch ^ (row & 3)) * 8);
    }
    int aOff[TM], bOff[TN];
    #pragma unroll
    for (int m = 0; m < TM; ++m) {
        int row = wr * (BM / 2) + m * 16 + fr;
        aOff[m] = row * 64 + ((fc ^ (row & 3)) * 16);
    }
    #pragma unroll
    for (int n = 0; n < TN; ++n) {
        int row = wc * (BN / 2) + n * 16 + fr;
        bOff[n] = row * 64 + ((fc ^ (row & 3)) * 16);
    }

    auto stageTo = [&](int buf, int kt) {
        #pragma unroll
        for (int it = 0; it < AIT; ++it)
            gl2lds16(aSrc[it] + kt, AsB + buf * ABY + it * 4096 + wv * 1024);
        #pragma unroll
        for (int it = 0; it < BIT; ++it)
            gl2lds16(bSrc[it] + kt, BsB + buf * BBY + it * 4096 + wv * 1024);
    };

    const int nt = K >> 5;
    stageTo(0, 0);
    asm volatile("s_waitcnt vmcnt(0)" ::: "memory");
    __builtin_amdgcn_s_barrier();
    asm volatile("" ::: "memory");

    int cur = 0;
    for (int t = 0; t < nt; ++t) {
        if (t + 1 < nt) stageTo(cur ^ 1, (t + 1) * 32);
        bf16x8 a[TM], b2[TN];
        #pragma unroll
        for (int m = 0; m < TM; ++m) a[m] = *(const bf16x8*)(AsB + cur * ABY + aOff[m]);
        #pragma unroll
        for (int n = 0; n < TN; ++n) b2[n] = *(const bf16x8*)(BsB + cur * BBY + bOff[n]);
        __builtin_amdgcn_s_setprio(1);
        #pragma unroll
        for (int m = 0; m < TM; ++m)
            #pragma unroll
            for (int n = 0; n < TN; ++n)
                acc[m][n] = __builtin_amdgcn_mfma_f32_16x16x32_bf16(a[m], b2[n], acc[m][n], 0, 0, 0);
        __builtin_amdgcn_s_setprio(0);
        if (t + 1 < nt) {
            asm volatile("s_waitcnt vmcnt(0)" ::: "memory");
            __builtin_amdgcn_s_barrier();
            asm volatile("" ::: "memory");
            cur ^= 1;
        }
    }

    #pragma unroll
    for (int n = 0; n < TN; ++n) {
        int col = col0 + wc * (BN / 2) + n * 16 + fr;
        float bb = bias ? bias[col] : 0.f;
        #pragma unroll
        for (int m = 0; m < TM; ++m) {
            int rbase = row0 + wr * (BM / 2) + m * 16 + fc * 4;
            #pragma unroll
            for (int rr = 0; rr < 4; ++rr) {
                float x = acc[m][n][rr] + bb;
                if constexpr (ACT) x = fmaxf(x, 0.f);
                long long ci = (long long)(rbase + rr) * ldc + col;
                if constexpr (CMODE == 0) Cf[ci] = x;
                else                      Cb[ci] = (bf16)x;
            }
        }
    }
}

// f32 -> bf16 bulk convert (8 elems/thread/iter, grid-stride)
__global__ __launch_bounds__(256)
void cvt_k(const float* __restrict__ in, bf16* __restrict__ outb, long long n8)
{
    long long i = (long long)blockIdx.x * 256 + threadIdx.x;
    const long long stride = (long long)gridDim.x * 256;
    for (; i < n8; i += stride) {
        const float* p = in + i * 8;
        float4 u = *(const float4*)p;
        float4 v = *(const float4*)(p + 4);
        bf16x8 w8;
        w8[0] = (bf16)u.x; w8[1] = (bf16)u.y; w8[2] = (bf16)u.z; w8[3] = (bf16)u.w;
        w8[4] = (bf16)v.x; w8[5] = (bf16)v.y; w8[6] = (bf16)v.z; w8[7] = (bf16)v.w;
        *(bf16x8*)(outb + i * 8) = w8;
    }
}

// W [K][N] f32  ->  WT [N][K] bf16   (32x32 LDS tiles)
__global__ __launch_bounds__(256)
void wt_k(const float* __restrict__ W, bf16* __restrict__ WT, int K, int N)
{
    __shared__ float t[32][33];
    int n0 = blockIdx.x * 32, k0 = blockIdx.y * 32;
    int r = threadIdx.x >> 3, c4 = (threadIdx.x & 7) * 4;
    float4 v = *(const float4*)&W[(long long)(k0 + r) * N + n0 + c4];
    t[r][c4 + 0] = v.x; t[r][c4 + 1] = v.y;
    t[r][c4 + 2] = v.z; t[r][c4 + 3] = v.w;
    __syncthreads();
    int n = threadIdx.x >> 3, kk4 = (threadIdx.x & 7) * 4;
    bf16x4 o;
    o[0] = (bf16)t[kk4 + 0][n]; o[1] = (bf16)t[kk4 + 1][n];
    o[2] = (bf16)t[kk4 + 2][n]; o[3] = (bf16)t[kk4 + 3][n];
    *(bf16x4*)&WT[(long long)(n0 + n) * K + k0 + kk4] = o;
}

// pack bq|bk|bv -> qkvB[2][1536]
__global__ __launch_bounds__(512)
void packb_k(const float* __restrict__ bq, const float* __restrict__ bk,
             const float* __restrict__ bv, float* __restrict__ dst)
{
    int l = blockIdx.x, t = threadIdx.x;
    dst[l * 1536 + t]        = bq[l * 512 + t];
    dst[l * 1536 + 512 + t]  = bk[l * 512 + t];
    dst[l * 1536 + 1024 + t] = bv[l * 512 + t];
}

// VT[h][d][s] = qkv[s][1024 + h*64 + d]   (bf16 64x64 LDS transpose)
__global__ __launch_bounds__(256)
void vt_k(const bf16* __restrict__ qkv, bf16* __restrict__ VT)
{
    __shared__ bf16 t[64][80];
    int h = blockIdx.y, s0 = blockIdx.x * 64;
    int r = threadIdx.x >> 2, c16 = (threadIdx.x & 3) * 16;
    const bf16* src = qkv + (long long)(s0 + r) * 1536 + 1024 + h * 64 + c16;
    *(bf16x8*)&t[r][c16]     = *(const bf16x8*)src;
    *(bf16x8*)&t[r][c16 + 8] = *(const bf16x8*)(src + 8);
    __syncthreads();
    int d = r, seg = c16;
    bf16 tmp[16];
    #pragma unroll
    for (int j = 0; j < 16; ++j) tmp[j] = t[seg + j][d];
    bf16* dst = VT + ((long long)(h * 64 + d)) * 512 + s0 + seg;
    *(bf16x8*)dst       = *(bf16x8*)&tmp[0];
    *(bf16x8*)(dst + 8) = *(bf16x8*)&tmp[8];
}

// masked-scale softmax: f32 scores in, bf16 probs out (full row incl. masked)
__global__ __launch_bounds__(256)
void softmax_k(const float* __restrict__ sc, bf16* __restrict__ pr)
{
    int row = blockIdx.x, h = blockIdx.y;
    const float* p = sc + ((long long)(h * SEQ + row)) * SEQ;
    bf16* o = pr + ((long long)(h * SEQ + row)) * SEQ;
    int tid = threadIdx.x;
    int j1 = tid + 256;
    float v0 = 0.f, v1 = 0.f;
    if (tid <= row) v0 = p[tid] * 0.125f;
    if (j1  <= row) v1 = p[j1]  * 0.125f;
    float m = fmaxf(v0, v1);
    #pragma unroll
    for (int off = 32; off; off >>= 1) m = fmaxf(m, __shfl_xor(m, off));
    __shared__ float red[4];
    if ((tid & 63) == 0) red[tid >> 6] = m;
    __syncthreads();
    m = fmaxf(fmaxf(red[0], red[1]), fmaxf(red[2], red[3]));
    float e0 = __expf(v0 - m);
    float e1 = __expf(v1 - m);
    float s = e0 + e1;
    #pragma unroll
    for (int off = 32; off; off >>= 1) s += __shfl_xor(s, off);
    __syncthreads();
    if ((tid & 63) == 0) red[tid >> 6] = s;
    __syncthreads();
    s = red[0] + red[1] + red[2] + red[3];
    float inv = 1.f / s;
    o[tid] = (bf16)(e0 * inv);
    o[j1]  = (bf16)(e1 * inv);
}

// x[row] = LN(x[row] + res[row & mask]) ; all bf16 storage, f32 math
__global__ __launch_bounds__(128)
void addln_k(bf16* __restrict__ xb, const bf16* __restrict__ res,
             unsigned resMask, const float* __restrict__ g,
             const float* __restrict__ bta)
{
    long long row = blockIdx.x;
    int tid = threadIdx.x;
    int c = tid * 4;
    bf16x4 xv4 = *(const bf16x4*)&xb[row * 512 + c];
    bf16x4 rv4 = *(const bf16x4*)&res[(long long)(blockIdx.x & resMask) * 512 + c];
    float x0 = (float)xv4[0] + (float)rv4[0];
    float x1 = (float)xv4[1] + (float)rv4[1];
    float x2 = (float)xv4[2] + (float)rv4[2];
    float x3 = (float)xv4[3] + (float)rv4[3];
    float s = x0 + x1 + x2 + x3;
    float qq = x0 * x0 + x1 * x1 + x2 * x2 + x3 * x3;
    #pragma unroll
    for (int off = 32; off; off >>= 1) {
        s += __shfl_xor(s, off);
        qq += __shfl_xor(qq, off);
    }
    __shared__ float rs[2], rq[2];
    if ((tid & 63) == 0) { rs[tid >> 6] = s; rq[tid >> 6] = qq; }
    __syncthreads();
    s = rs[0] + rs[1]; qq = rq[0] + rq[1];
    float mean = s * (1.0f / 512.0f);
    float var  = qq * (1.0f / 512.0f) - mean * mean;
    float rstd = rsqrtf(var + 1e-5f);
    float4 gv = *(const float4*)&g[c];
    float4 bv = *(const float4*)&bta[c];
    bf16x4 o4;
    o4[0] = (bf16)((x0 - mean) * rstd * gv.x + bv.x);
    o4[1] = (bf16)((x1 - mean) * rstd * gv.y + bv.y);
    o4[2] = (bf16)((x2 - mean) * rstd * gv.z + bv.z);
    o4[3] = (bf16)((x3 - mean) * rstd * gv.w + bv.w);
    *(bf16x4*)&xb[row * 512 + c] = o4;
}

// out[row] = dot(x[row,:], fcW) + fcb   (x bf16)
__global__ __launch_bounds__(256)
void fc_k(const bf16* __restrict__ x, const float* __restrict__ w,
          const float* __restrict__ bb, float* __restrict__ out)
{
    int row  = blockIdx.x * 4 + (threadIdx.x >> 6);
    int lane = threadIdx.x & 63;
    const bf16* xr = x + (long long)row * 512;
    bf16x8 a8 = *(const bf16x8*)&xr[lane * 8];
    float4 w0 = *(const float4*)&w[lane * 8];
    float4 w1 = *(const float4*)&w[lane * 8 + 4];
    float s = (float)a8[0] * w0.x + (float)a8[1] * w0.y
            + (float)a8[2] * w0.z + (float)a8[3] * w0.w
            + (float)a8[4] * w1.x + (float)a8[5] * w1.y
            + (float)a8[6] * w1.z + (float)a8[7] * w1.w;
    #pragma unroll
    for (int off = 32; off; off >>= 1) s += __shfl_xor(s, off);
    if (lane == 0) out[row] = s + bb[0];
}

extern "C" void kernel_launch(void* const* d_in, const int* in_sizes, int n_in,
                              void* d_out, int out_size, void* d_ws, size_t ws_size,
                              hipStream_t stream)
{
    const float* input_seq = (const float*)d_in[0];
    const float* emb_W  = (const float*)d_in[1];
    const float* emb_b  = (const float*)d_in[2];
    const float* pos_emb= (const float*)d_in[3];
    const float* Wq = (const float*)d_in[4];
    const float* bq = (const float*)d_in[5];
    const float* Wk = (const float*)d_in[6];
    const float* bk = (const float*)d_in[7];
    const float* Wv = (const float*)d_in[8];
    const float* bv = (const float*)d_in[9];
    const float* Wo = (const float*)d_in[10];
    const float* bo = (const float*)d_in[11];
    const float* ln1_g = (const float*)d_in[12];
    const float* ln1_b = (const float*)d_in[13];
    const float* W1 = (const float*)d_in[14];
    const float* b1 = (const float*)d_in[15];
    const float* W2 = (const float*)d_in[16];
    const float* b2 = (const float*)d_in[17];
    const float* ln2_g = (const float*)d_in[18];
    const float* ln2_b = (const float*)d_in[19];
    const float* fcW = (const float*)d_in[20];
    const float* fcb = (const float*)d_in[21];
    float* out = (float*)d_out;

    // ---- workspace layout ----
    char* w = (char*)d_ws;
    size_t off = 0;
    auto alloc = [&](size_t bytes) -> void* {
        off = (off + 255) & ~(size_t)255;
        void* p = w + off;
        off += bytes;
        return p;
    };
    bf16*  xb     = (bf16*) alloc(16384ull * 512 * 2);   // 16 MB
    bf16*  embWT  = (bf16*) alloc(512ull * 2048 * 2);
    bf16*  qkvWT  = (bf16*) alloc(2ull * 1536 * 512 * 2);
    bf16*  WoT    = (bf16*) alloc(2ull * 512 * 512 * 2);
    bf16*  W1T    = (bf16*) alloc(2ull * 2048 * 512 * 2);
    bf16*  W2T    = (bf16*) alloc(2ull * 512 * 2048 * 2);
    float* qkvB   = (float*)alloc(2ull * 1536 * 4);
    off = (off + 255) & ~(size_t)255;
    char* dynp = w + off;
    // overlay 1 (embedding phase): input_seq as bf16, 64 MB
    bf16*  seqb     = (bf16*)dynp;                         // 16384 x 2048
    // overlay 2 (attention phase, ~16 MB)
    bf16*  qkv      = (bf16*)dynp;                         // 512x1536
    float* scores   = (float*)(dynp + 1572864);            // 8x512x512 f32
    bf16*  probs    = (bf16*)(dynp + 1572864 + 8388608);   // 8x512x512 bf16
    bf16*  VT       = (bf16*)(dynp + 1572864 + 8388608 + 4194304);
    bf16*  attn0b   = (bf16*)(dynp + 1572864 + 8388608 + 4194304 + 524288);
    bf16*  attnout0b= (bf16*)(dynp + 1572864 + 8388608 + 4194304 + 524288 + 524288);
    // overlay 3 (FFN phase): hidden bf16 [16384][2048] + ffout bf16 [16384][512]
    bf16*  hidden = (bf16*)dynp;                           // 67 MB
    bf16*  ffout  = (bf16*)(dynp + 16384ull * 2048 * 2);   // 16 MB

    dim3 blk(256);
    dim3 blk512(512);

    // ---- weight conversion (transposed bf16) + input conversion ----
    wt_k<<<dim3(16, 64), blk, 0, stream>>>(emb_W, embWT, 2048, 512);
    for (int l = 0; l < 2; ++l) {
        wt_k<<<dim3(16, 16), blk, 0, stream>>>(Wq + l * 262144, qkvWT + l * 786432,          512, 512);
        wt_k<<<dim3(16, 16), blk, 0, stream>>>(Wk + l * 262144, qkvWT + l * 786432 + 262144, 512, 512);
        wt_k<<<dim3(16, 16), blk, 0, stream>>>(Wv + l * 262144, qkvWT + l * 786432 + 524288, 512, 512);
        wt_k<<<dim3(16, 16), blk, 0, stream>>>(Wo + l * 262144, WoT + l * 262144, 512, 512);
        wt_k<<<dim3(64, 16), blk, 0, stream>>>(W1 + l * 1048576, W1T + l * 1048576, 512, 2048);
        wt_k<<<dim3(16, 64), blk, 0, stream>>>(W2 + l * 1048576, W2T + l * 1048576, 2048, 512);
    }
    packb_k<<<dim3(2), dim3(512), 0, stream>>>(bq, bk, bv, qkvB);
    cvt_k<<<dim3(2048), blk, 0, stream>>>(input_seq, seqb, 16384ll * 2048 / 8);

    // ---- embedding: xb = seqb @ emb_W + emb_b + pos_emb ----
    mgemm2<128, 128, 0, 1, 4><<<dim3(4, 128), blk512, 0, stream>>>(
        seqb, 2048, embWT, 2048, emb_b, pos_emb, xb, 512, 2048);

    for (int l = 0; l < 2; ++l) {
        const bf16* qkvWT_l = qkvWT + l * 786432;
        const bf16* WoT_l   = WoT + l * 262144;
        const bf16* W1T_l   = W1T + l * 1048576;
        const bf16* W2T_l   = W2T + l * 1048576;

        // QKV projection (batch 0 rows only), packed N=1536, bf16 out
        mgemm<128, 128, 0, 1, 0><<<dim3(12, 4), blk, 0, stream>>>(
            xb, 512, 0, qkvWT_l, 512, 0, qkvB + l * 1536,
            nullptr, qkv, 1536, 0, 512);
        // scores[h] = Qh @ Kh^T (causal tile skip), f32 out
        mgemm<128, 128, 0, 0, 1><<<dim3(4, 4, 8), blk, 0, stream>>>(
            qkv, 1536, 64, qkv + 512, 1536, 64, nullptr,
            scores, nullptr, 512, 262144, 64);
        softmax_k<<<dim3(512, 8), blk, 0, stream>>>(scores, probs);
        vt_k<<<dim3(8, 8), blk, 0, stream>>>(qkv, VT);
        // attn0 = probs @ V (per head, N=64), bf16 out
        mgemm<128, 64, 0, 1, 0><<<dim3(1, 4, 8), blk, 0, stream>>>(
            probs, 512, 262144, VT, 512, 32768, nullptr,
            nullptr, attn0b, 512, 64, 512);
        // attnout0 = attn0 @ Wo + bo, bf16 out
        mgemm<128, 128, 0, 1, 0><<<dim3(4, 4), blk, 0, stream>>>(
            attn0b, 512, 0, WoT_l, 512, 0, bo + l * 512, nullptr,
            attnout0b, 512, 0, 512);
        // x = LN1(x + attnout0[s]) broadcast
        addln_k<<<dim3(16384), dim3(128), 0, stream>>>(
            xb, attnout0b, 511u, ln1_g + l * 512, ln1_b + l * 512);

        // ---- FFN (full, unchunked) ----
        mgemm2<256, 256, 1, 0, 2><<<dim3(8, 64), blk512, 0, stream>>>(
            xb, 512, W1T_l, 512, b1 + l * 2048, nullptr, hidden, 2048, 512);
        mgemm2<128, 128, 0, 0, 4><<<dim3(4, 128), blk512, 0, stream>>>(
            hidden, 2048, W2T_l, 2048, b2 + l * 512, nullptr, ffout, 512, 2048);
        addln_k<<<dim3(16384), dim3(128), 0, stream>>>(
            xb, ffout, 0xffffffffu, ln2_g + l * 512, ln2_b + l * 512);
    }

    // ---- out = x @ fc_W + fc_b ----
    fc_k<<<dim3(4096), blk, 0, stream>>>(xb, fcW, fcb, out);
}